// Round 6
// baseline (323.953 us; speedup 1.0000x reference)
//
#include <hip/hip_runtime.h>
#include <hip/hip_bf16.h>

typedef __attribute__((ext_vector_type(8))) short short8;
typedef __attribute__((ext_vector_type(4))) float f32x4;

__device__ __forceinline__ ushort f2bf(float x) {
    union { __hip_bfloat16 hh; ushort u; } cv;
    cv.hh = __float2bfloat16(x);
    return cv.u;
}

// ---------------------------------------------------------------------------
// Kernel 1: prep — bf16-cast a/b, compute feature maps fa/fb (fp32 -> bf16),
// and fp32 row squared-norms. Packed layout: [row][96] = [a(64) | fa(32)].
// ---------------------------------------------------------------------------
__global__ __launch_bounds__(256) void prep_kernel(
    const float* __restrict__ a, const float* __restrict__ b,
    const float* __restrict__ W1, const float* __restrict__ b1v,
    const float* __restrict__ W2, const float* __restrict__ b2v,
    ushort* __restrict__ af, ushort* __restrict__ bfp,
    float* __restrict__ asq, float* __restrict__ bsq)
{
    __shared__ float sW1[32][65];
    __shared__ float sW2[32][33];
    __shared__ float sB1[32];
    __shared__ float sB2[32];
    __shared__ float sX[16][64];
    __shared__ float sH[16][33];

    const int t = threadIdx.x;
    for (int i = t; i < 32 * 64; i += 256) sW1[i >> 6][i & 63] = W1[i];
    for (int i = t; i < 32 * 32; i += 256) sW2[i >> 5][i & 31] = W2[i];
    if (t < 32) { sB1[t] = b1v[t]; sB2[t] = b2v[t]; }

    const int rowBase = blockIdx.x * 16;   // blocks never straddle a/b
    const float* src; ushort* dstf; float* dsq; int row0;
    if (rowBase < 8192) { src = a; dstf = af;  dsq = asq; row0 = rowBase; }
    else                { src = b; dstf = bfp; dsq = bsq; row0 = rowBase - 8192; }

    // vectorized load: 256 threads x 1 float4 = 16 rows x 64 cols
    {
        const int r = t >> 4, c = t & 15;
        f32x4 v = *(const f32x4*)(src + (size_t)(row0 + r) * 64 + c * 4);
        *(f32x4*)&sX[r][c * 4] = v;
        ushort4 uu;
        uu.x = f2bf(v.x); uu.y = f2bf(v.y); uu.z = f2bf(v.z); uu.w = f2bf(v.w);
        *(ushort4*)(dstf + (size_t)(row0 + r) * 96 + c * 4) = uu;
    }
    __syncthreads();

    // layer 1: h = tanh(x @ W1^T + b1)
    for (int i = t; i < 16 * 32; i += 256) {
        int r = i >> 5, j = i & 31;
        float acc = sB1[j];
        #pragma unroll
        for (int k = 0; k < 64; ++k) acc += sX[r][k] * sW1[j][k];
        sH[r][j] = tanhf(acc);
    }
    __syncthreads();

    // layer 2: f = h @ W2^T + b2 -> bf16
    for (int i = t; i < 16 * 32; i += 256) {
        int r = i >> 5, j = i & 31;
        float acc = sB2[j];
        #pragma unroll
        for (int k = 0; k < 32; ++k) acc += sH[r][k] * sW2[j][k];
        dstf[(size_t)(row0 + r) * 96 + 64 + j] = f2bf(acc);
    }

    // fp32 squared norms (exact)
    if (t < 16) {
        float s = 0.f;
        #pragma unroll
        for (int k = 0; k < 64; ++k) s += sX[t][k] * sX[t][k];
        dsq[row0 + t] = s;
    }
}

// ---------------------------------------------------------------------------
// Kernel 2 v4: barrier-free row-slab dual-Gram. 512 blocks x 16 a-rows;
// 4 waves/block each independently sweep a disjoint 2048-col range of b in
// 16 steps of 128 cols. NO LDS, NO barriers: A-frags and B-frags load
// straight from L2 (af 3KB/block, bfp 1.5MB fully L2-resident). Swapped
// MFMA (D = b-frag x a-frag, layout verified R4) puts 4 consecutive output
// cols per lane -> per row each wave emits one sequential write stream.
// Exactly 2 blocks/CU, one round, stores pipelined across the whole kernel.
// ---------------------------------------------------------------------------
__global__ __launch_bounds__(256) void gram_kernel(
    const ushort* __restrict__ af, const ushort* __restrict__ bfp,
    const float* __restrict__ asq, const float* __restrict__ bsq,
    float* __restrict__ out)
{
    const int t = threadIdx.x;
    const int lane = t & 63;
    const int w = t >> 6;                 // wave 0..3 -> col range
    const int lr = lane & 15, lk = lane >> 4;

    const int myrow = (blockIdx.x << 4) + lr;       // a-row owned by this lane
    const size_t rowbase = (size_t)myrow * 8192;

    // A fragments: lane holds a[myrow][ks*32 + lk*8 .. +8)
    const ushort* ap = af + (size_t)myrow * 96 + lk * 8;
    short8 aF0 = *(const short8*)(ap);
    short8 aF1 = *(const short8*)(ap + 32);
    short8 aF2 = *(const short8*)(ap + 64);
    const float av = asq[myrow];

    for (int ct = 0; ct < 16; ++ct) {
        const int C0 = (w << 11) + (ct << 7);       // this wave's 128-col chunk

        // B fragments for 8 n-tiles (16 cols each), straight from L2
        short8 bF0[8], bF1[8], bF2[8];
        #pragma unroll
        for (int n = 0; n < 8; ++n) {
            const ushort* bp = bfp + (size_t)(C0 + n * 16 + lr) * 96 + lk * 8;
            bF0[n] = *(const short8*)(bp);
            bF1[n] = *(const short8*)(bp + 32);
            bF2[n] = *(const short8*)(bp + 64);
        }

        f32x4 accd[8], accq[8];
        #pragma unroll
        for (int n = 0; n < 8; ++n) {
            accd[n] = (f32x4){0.f, 0.f, 0.f, 0.f};
            accq[n] = (f32x4){0.f, 0.f, 0.f, 0.f};
        }
        #pragma unroll
        for (int n = 0; n < 8; ++n) {
            // D = b·a^T: out[row = a-row via lr][col = b-row tile via lk*4+j]
            accd[n] = __builtin_amdgcn_mfma_f32_16x16x32_bf16(bF0[n], aF0, accd[n], 0, 0, 0);
            accd[n] = __builtin_amdgcn_mfma_f32_16x16x32_bf16(bF1[n], aF1, accd[n], 0, 0, 0);
            accq[n] = __builtin_amdgcn_mfma_f32_16x16x32_bf16(bF2[n], aF2, accq[n], 0, 0, 0);
        }

        #pragma unroll
        for (int n = 0; n < 8; ++n) {
            const int colb = C0 + n * 16 + lk * 4;
            const f32x4 bs = *(const f32x4*)(bsq + colb);
            f32x4 v;
            #pragma unroll
            for (int j = 0; j < 4; ++j) {
                const float sq = av + bs[j] - 2.0f * accd[n][j];
                const float rbf = __expf(-fmaxf(sq, 0.0f));
                v[j] = 0.5f * accq[n][j] + 0.5f * rbf;
            }
            *(f32x4*)(out + rowbase + colb) = v;
        }
    }
}

// ---------------------------------------------------------------------------
extern "C" void kernel_launch(void* const* d_in, const int* in_sizes, int n_in,
                              void* d_out, int out_size, void* d_ws, size_t ws_size,
                              hipStream_t stream)
{
    const float* a  = (const float*)d_in[0];
    const float* b  = (const float*)d_in[1];
    const float* W1 = (const float*)d_in[2];
    const float* b1 = (const float*)d_in[3];
    const float* W2 = (const float*)d_in[4];
    const float* b2 = (const float*)d_in[5];
    float* out = (float*)d_out;

    char* ws = (char*)d_ws;
    ushort* af  = (ushort*)(ws);                              // 8192*96 bf16
    ushort* bfp = (ushort*)(ws + (size_t)8192 * 96 * 2);      // 8192*96 bf16
    float*  asq = (float*)(ws + (size_t)2 * 8192 * 96 * 2);
    float*  bsq = (float*)(ws + (size_t)2 * 8192 * 96 * 2 + 8192 * 4);

    prep_kernel<<<1024, 256, 0, stream>>>(a, b, W1, b1, W2, b2, af, bfp, asq, bsq);
    gram_kernel<<<512, 256, 0, stream>>>(af, bfp, asq, bsq, out);
}